// Round 8
// baseline (100.729 us; speedup 1.0000x reference)
//
#include <hip/hip_runtime.h>
#include <hip/hip_cooperative_groups.h>

namespace cg = cooperative_groups;

// popcount of ballot bits strictly below this lane (wave64)
__device__ __forceinline__ int lanes_below(unsigned long long m) {
    return __builtin_amdgcn_mbcnt_hi((unsigned)(m >> 32),
           __builtin_amdgcn_mbcnt_lo((unsigned)m, 0u));
}

// Masked MSE with ragged alignment — single cooperative kernel.
// 512 blocks x 512 threads, 8 rows per block (row = blockIdx + it*512).
// Per row: R5's branch-free path — 4 independent vector loads, rank via
// ballot+mbcnt, all 8 gather addresses computed with pure VALU, 8 independent
// gather loads, select-masked FMAs. Row partial -> row_sums[row].
// Then grid.sync() and block 0 reduces the 4096 partials (no 2nd launch,
// no contended atomics).
__global__ __launch_bounds__(512, 8) void masked_mse_all(
    const float* __restrict__ pred,
    const float* __restrict__ target,
    const int*   __restrict__ mask,
    float*       __restrict__ row_sums,
    float*       __restrict__ out,
    int S, int B, int rows_per_block)
{
    const int tid  = threadIdx.x;
    const int lane = tid & 63;
    const int wid  = tid >> 6;          // 0..7

    __shared__ int   tsum[16];
    __shared__ float facc[8];

    for (int it = 0; it < rows_per_block; ++it) {
        const int row = blockIdx.x + it * gridDim.x;
        if (row < B) {
            const float4* __restrict__ p4 = reinterpret_cast<const float4*>(pred + (size_t)row * S);
            const int4*   __restrict__ m4 = reinterpret_cast<const int4*>(mask + (size_t)row * S);
            const float*  __restrict__ trow = target + (size_t)row * S;

            // all four big loads independent, issued together
            const int4   ma = m4[tid];
            const int4   mb = m4[tid + 512];
            const float4 pa = p4[tid];
            const float4 pb = p4[tid + 512];

            const int c0 = (ma.x != 0), c1 = (ma.y != 0), c2 = (ma.z != 0), c3 = (ma.w != 0);
            const int c4 = (mb.x != 0), c5 = (mb.y != 0), c6 = (mb.z != 0), c7 = (mb.w != 0);

            const unsigned long long a0 = __ballot(c0);
            const unsigned long long a1 = __ballot(c1);
            const unsigned long long a2 = __ballot(c2);
            const unsigned long long a3 = __ballot(c3);
            const unsigned long long b0 = __ballot(c4);
            const unsigned long long b1 = __ballot(c5);
            const unsigned long long b2 = __ballot(c6);
            const unsigned long long b3 = __ballot(c7);

            const int pref_a = lanes_below(a0) + lanes_below(a1) + lanes_below(a2) + lanes_below(a3);
            const int pref_b = lanes_below(b0) + lanes_below(b1) + lanes_below(b2) + lanes_below(b3);
            const int tot_a  = __popcll(a0) + __popcll(a1) + __popcll(a2) + __popcll(a3);
            const int tot_b  = __popcll(b0) + __popcll(b1) + __popcll(b2) + __popcll(b3);

            if (lane == 0) { tsum[wid] = tot_a; tsum[8 + wid] = tot_b; }
            __syncthreads();

            int base_a = 0, pre_b = 0, sumA = 0;
            #pragma unroll
            for (int w = 0; w < 8; ++w) {
                const int va = tsum[w], vb = tsum[8 + w];
                base_a += (w < wid) ? va : 0;
                pre_b  += (w < wid) ? vb : 0;
                sumA   += va;
            }
            const int base_b = sumA + pre_b;

            // branch-free: all 8 gather addresses first (pure VALU chain)
            int idx[8];
            {
                int r = base_a + pref_a;
                idx[0] = r; r += c0;
                idx[1] = r; r += c1;
                idx[2] = r; r += c2;
                idx[3] = r; r += c3;
            }
            {
                int r = base_b + pref_b;
                idx[4] = r; r += c4;
                idx[5] = r; r += c5;
                idx[6] = r; r += c6;
                idx[7] = r; r += c7;
            }
            float tv[8];
            #pragma unroll
            for (int j = 0; j < 8; ++j) tv[j] = trow[idx[j]];   // 8 independent loads

            const float pv[8] = {pa.x, pa.y, pa.z, pa.w, pb.x, pb.y, pb.z, pb.w};
            const int   cs[8] = {c0, c1, c2, c3, c4, c5, c6, c7};
            float acc = 0.0f;
            #pragma unroll
            for (int j = 0; j < 8; ++j) {
                const float d = pv[j] - tv[j];
                acc += cs[j] ? d * d : 0.0f;
            }

            // wave reduce, then cross-wave via LDS
            #pragma unroll
            for (int off = 32; off > 0; off >>= 1) acc += __shfl_down(acc, off, 64);
            if (lane == 0) facc[wid] = acc;
            __syncthreads();
            if (tid == 0) {
                float s = 0.0f;
                #pragma unroll
                for (int w = 0; w < 8; ++w) s += facc[w];
                row_sums[row] = s;
            }
            __syncthreads();   // tsum/facc reused next row (WAR)
        }
    }

    // grid-wide barrier, then block 0 reduces the row partials
    cg::this_grid().sync();

    if (blockIdx.x == 0) {
        float acc = 0.0f;
        const int n4 = B >> 2;
        const float4* rs4 = reinterpret_cast<const float4*>(row_sums);
        for (int i = tid; i < n4; i += 512) {
            float4 v = rs4[i];
            acc += (v.x + v.y) + (v.z + v.w);
        }
        for (int i = (n4 << 2) + tid; i < B; i += 512) acc += row_sums[i];

        #pragma unroll
        for (int off = 32; off > 0; off >>= 1) acc += __shfl_down(acc, off, 64);
        if (lane == 0) facc[wid] = acc;
        __syncthreads();
        if (tid == 0) {
            float s = 0.0f;
            #pragma unroll
            for (int w = 0; w < 8; ++w) s += facc[w];
            out[0] = s;
        }
    }
}

extern "C" void kernel_launch(void* const* d_in, const int* in_sizes, int n_in,
                              void* d_out, int out_size, void* d_ws, size_t ws_size,
                              hipStream_t stream) {
    const float* pred   = (const float*)d_in[0];
    const float* target = (const float*)d_in[1];
    const int*   mask   = (const int*)d_in[2];
    float* out = (float*)d_out;
    float* row_sums = (float*)d_ws;

    int S = 4096;
    int B = in_sizes[0] / S;
    const int nblocks = 512;                       // 2 blocks/CU -> co-resident
    int rows_per_block = (B + nblocks - 1) / nblocks;

    void* args[] = { (void*)&pred, (void*)&target, (void*)&mask,
                     (void*)&row_sums, (void*)&out, (void*)&S, (void*)&B,
                     (void*)&rows_per_block };
    hipLaunchCooperativeKernel((void*)masked_mse_all, dim3(nblocks), dim3(512),
                               args, 0, stream);
}